// Round 5
// baseline (1332.691 us; speedup 1.0000x reference)
//
#include <hip/hip_runtime.h>

// VQ-VAE fused forward on gfx950 — v5 (pipelined weight streams).
// v4 base (proto-folded scoring, frag-order weights, 40 KB LDS, 4 blocks/CU,
// XCD swizzle, full-line x/out). New:
//  - G4: 16-proto groups, NAMED double-buffered frag regs (pA/pB), next-group
//    global loads issued under current group's MFMAs (no barriers in the span).
//  - G3: same pattern (mA/mB over 4 half-groups); G4's first 2 groups preload
//    under G3's last compute; G3's buffers preload under G2.
//  - G1: x staged through hB (free during G1) in 2 chunks of 256 K-cols:
//    barriers 16 -> 4, 8-deep batched NT loads.
//  - s_setprio(1) around MFMA clusters.
// Attacks the latency-bound serial chain (VGPR_Count=64 showed the compiler
// was NOT keeping weight frags resident -> no software pipeline, re-fetches).

typedef unsigned short u16;
typedef float f32x4 __attribute__((ext_vector_type(4)));
typedef __bf16 bf16x8 __attribute__((ext_vector_type(8)));
typedef unsigned short u16x8 __attribute__((ext_vector_type(8)));
typedef unsigned short u16x4 __attribute__((ext_vector_type(4)));

#define N_ROWS 131072
#define IN_D 512
#define HID_D 64
#define OUT_D 256
#define K_P 1024

__device__ __forceinline__ u16 f2bfn(float f) {
  return __builtin_bit_cast(u16, (__bf16)f);
}
__device__ __forceinline__ f32x4 mfma16(u16x8 a, u16x8 b, f32x4 c) {
  return __builtin_amdgcn_mfma_f32_16x16x32_bf16(
      __builtin_bit_cast(bf16x8, a), __builtin_bit_cast(bf16x8, b), c, 0, 0, 0);
}
// XOR-swizzled LDS addressing (u16 units), 8-col chunks stay contiguous.
__device__ __forceinline__ int sw64(int row, int col) {   // [64][64]
  return row * 64 + ((((col >> 3) ^ (row & 7)) & 7) << 3) + (col & 7);
}
__device__ __forceinline__ int sw256(int row, int col) {  // [64][256]
  return row * 256 + ((((col >> 3) ^ (row & 15)) & 31) << 3) + (col & 7);
}

// ---------------- prep kernels (unchanged from v4) ----------------
__global__ void prep_w(const float* __restrict__ W1, const float* __restrict__ W2,
                       const float* __restrict__ Wmu, u16* __restrict__ w1a,
                       u16* __restrict__ w2a, u16* __restrict__ wmua,
                       float* __restrict__ loss_accum) {
  int i = blockIdx.x * 256 + threadIdx.x;   // grid 448*256 = 114688 exactly
  if (i == 0) *loss_accum = 0.f;
  if (i < 32768) {                          // W1: f = w*16+s  (64 frags)
    int a = i;
    int f = a >> 9, r = (a >> 5) & 15, c = a & 31;
    int w = f >> 4, s = f & 15;
    w1a[a] = f2bfn(W1[(w * 16 + r) * IN_D + s * 32 + c]);
  } else if (i < 49152) {                   // W2: f = w*8+nt*2+s  (32 frags)
    int a = i - 32768;
    int f = a >> 9, r = (a >> 5) & 15, c = a & 31;
    int w = f >> 3, nt = (f >> 1) & 3, s = f & 1;
    w2a[a] = f2bfn(W2[(w * 64 + nt * 16 + r) * HID_D + s * 32 + c]);
  } else {                                  // Wmu: f = w*32+g2*8+s (128 frags)
    int a = i - 49152;
    int f = a >> 9, r = (a >> 5) & 15, c = a & 31;
    int w = f >> 5, g2 = (f >> 3) & 3, s = f & 7;
    wmua[a] = f2bfn(Wmu[(w * 64 + g2 * 16 + r) * OUT_D + s * 32 + c]);
  }
}

__global__ void prep_p(const float* __restrict__ protos, const float* __restrict__ Wmu,
                       const float* __restrict__ bmu, u16* __restrict__ p2a,
                       float* __restrict__ cinit) {
  __shared__ float prow[4][256];
  const int b = blockIdx.x, t = threadIdx.x;   // 256 blocks x 4 protos
  const int wv = t >> 6, lane = t & 63;
  #pragma unroll
  for (int i = 0; i < 4; i++) prow[i][t] = protos[(b * 4 + i) * 256 + t];
  __syncthreads();
  float acc[4] = {0.f, 0.f, 0.f, 0.f};
  #pragma unroll 4
  for (int j = 0; j < 256; j++) {
    float w = Wmu[j * 256 + t];
    acc[0] += prow[0][j] * w; acc[1] += prow[1][j] * w;
    acc[2] += prow[2][j] * w; acc[3] += prow[3][j] * w;
  }
  #pragma unroll
  for (int i = 0; i < 4; i++) {
    int p = b * 4 + i;
    int f = (p >> 8) * 128 + ((p >> 5) & 7) * 16 + ((p >> 4) & 1) * 8 + (t >> 5);
    p2a[f * 512 + (p & 15) * 32 + (t & 31)] = f2bfn(acc[i]);
  }
  float part = 0.f;
  #pragma unroll
  for (int c = 0; c < 4; c++) {
    float v = prow[wv][lane + c * 64];
    part += v * bmu[lane + c * 64] - 0.5f * v * v;
  }
  for (int off = 32; off; off >>= 1) part += __shfl_xor(part, off, 64);
  if (lane == 0) cinit[b * 4 + wv] = part;
}

__global__ void fin(const float* __restrict__ loss_accum, float* __restrict__ out) {
  out[(size_t)N_ROWS * OUT_D] = loss_accum[0] * (1.25f / ((float)N_ROWS * (float)OUT_D));
  out[(size_t)N_ROWS * OUT_D + 1] = 0.f;  // capacity
}

// ---------------- fused main kernel ----------------

// G3 half-group (16 lat cols): load frags / compute rownorm partials
#define LOAD_B3(buf, h)                                                         \
  {                                                                             \
    _Pragma("unroll")                                                           \
    for (int s = 0; s < 8; s++)                                                 \
      buf[s] = *((const u16x8*)(wmua + ((wave * 4 + (h)) * 8 + s) * 512 + fragoff)); \
  }

#define COMP_B3(buf, h)                                                         \
  {                                                                             \
    __builtin_amdgcn_s_setprio(1);                                              \
    _Pragma("unroll")                                                           \
    for (int mt = 0; mt < 4; mt++) {                                            \
      f32x4 acc = (f32x4){0.f, 0.f, 0.f, 0.f};                                  \
      _Pragma("unroll")                                                         \
      for (int s = 0; s < 8; s++) {                                             \
        u16x8 af = *((const u16x8*)(hB + sw256(mt * 16 + l15, s * 32 + quad * 8))); \
        acc = mfma16(af, buf[s], acc);                                          \
      }                                                                         \
      _Pragma("unroll")                                                         \
      for (int r = 0; r < 4; r++) {                                             \
        float v = acc[r] + bias3[h];                                            \
        rn[mt * 4 + r] += v * v;                                                \
      }                                                                         \
    }                                                                           \
    __builtin_amdgcn_s_setprio(0);                                              \
  }

// G4 16-proto group: load frags+cinit / compute packed-key argmax
#define LOAD_P(buf, cc, ii, gg)                                                 \
  {                                                                             \
    _Pragma("unroll")                                                           \
    for (int s = 0; s < 8; s++)                                                 \
      buf[s] = *((const u16x8*)(p2a + (wave * 128 + (gg) * 8 + s) * 512 + fragoff)); \
    cc = cinit[wave * 256 + (gg) * 16 + l15];                                   \
    ii = (unsigned)(wave * 256 + (gg) * 16 + l15);                              \
  }

#define COMP_P(buf, cc, ii)                                                     \
  {                                                                             \
    __builtin_amdgcn_s_setprio(1);                                              \
    _Pragma("unroll")                                                           \
    for (int mt = 0; mt < 4; mt++) {                                            \
      f32x4 acc = (f32x4){cc, cc, cc, cc};                                      \
      _Pragma("unroll")                                                         \
      for (int s = 0; s < 8; s++) {                                             \
        u16x8 af = *((const u16x8*)(hB + sw256(mt * 16 + l15, s * 32 + quad * 8))); \
        acc = mfma16(af, buf[s], acc);                                          \
      }                                                                         \
      _Pragma("unroll")                                                         \
      for (int r = 0; r < 4; r++) {                                             \
        unsigned kk = (__builtin_bit_cast(unsigned, acc[r]) & 0xFFFFFC00u) | ii; \
        mk[mt * 4 + r] = fmaxf(mk[mt * 4 + r], __builtin_bit_cast(float, kk));  \
      }                                                                         \
    }                                                                           \
    __builtin_amdgcn_s_setprio(0);                                              \
  }

__global__ __launch_bounds__(256, 4) void vq_fused(
    const float* __restrict__ x, const float* __restrict__ b1,
    const float* __restrict__ b2, const float* __restrict__ bmu,
    const float* __restrict__ protos, const u16* __restrict__ w1a,
    const u16* __restrict__ w2a, const u16* __restrict__ wmua,
    const u16* __restrict__ p2a, const float* __restrict__ cinit,
    float* __restrict__ out, float* __restrict__ loss_accum) {
  __shared__ uint4 smem4[2560];                  // 40 KB exactly -> 4 blocks/CU
  u16* hA = (u16*)smem4;                         // 8 KB: h1 -> scratch
  u16* hB = (u16*)smem4 + 4096;                  // 32 KB: x-chunks -> h2s

  const int tid = threadIdx.x;
  const int wave = tid >> 6;
  const int lane = tid & 63;
  const int quad = lane >> 4;
  const int l15 = lane & 15;
  const int fragoff = l15 * 32 + quad * 8;       // lane offset in a 512-u16 frag
  const int bid = blockIdx.x;
  const int swz = (bid & 7) * 256 + (bid >> 3);  // bijective XCD swizzle
  const long rowbase = (long)swz * 64;
  const int r8 = tid >> 3, c8 = tid & 7;         // 8 threads/row map

  // ===== GEMM1: h1 = relu(x @ W1^T + b1); 2 chunks of 256 K-cols via hB =====
  u16x8 w1f[16];
  #pragma unroll
  for (int s = 0; s < 16; s++)
    w1f[s] = *((const u16x8*)(w1a + (wave * 16 + s) * 512 + fragoff));

  f32x4 acc1[4];
  #pragma unroll
  for (int mt = 0; mt < 4; mt++) acc1[mt] = (f32x4){0.f, 0.f, 0.f, 0.f};

  #pragma unroll
  for (int c = 0; c < 2; c++) {
    if (c) __syncthreads();                      // prev chunk's frag reads done
    #pragma unroll
    for (int half = 0; half < 2; half++) {       // rows r8 and r8+32
      const float* xp = x + (rowbase + r8 + half * 32) * IN_D + c * 256 + c8 * 32;
      f32x4 v[8];
      #pragma unroll
      for (int q = 0; q < 8; q++)
        v[q] = __builtin_nontemporal_load((const f32x4*)xp + q);
      #pragma unroll
      for (int q2 = 0; q2 < 4; q2++) {
        u16x8 hv;
        hv[0] = f2bfn(v[2 * q2][0]); hv[1] = f2bfn(v[2 * q2][1]);
        hv[2] = f2bfn(v[2 * q2][2]); hv[3] = f2bfn(v[2 * q2][3]);
        hv[4] = f2bfn(v[2 * q2 + 1][0]); hv[5] = f2bfn(v[2 * q2 + 1][1]);
        hv[6] = f2bfn(v[2 * q2 + 1][2]); hv[7] = f2bfn(v[2 * q2 + 1][3]);
        *((u16x8*)(hB + sw256(r8 + half * 32, c8 * 32 + q2 * 8))) = hv;
      }
    }
    __syncthreads();                             // chunk staged
    __builtin_amdgcn_s_setprio(1);
    #pragma unroll
    for (int s = 0; s < 8; s++) {
      u16x8 bf = w1f[c * 8 + s];
      #pragma unroll
      for (int mt = 0; mt < 4; mt++) {
        u16x8 af = *((const u16x8*)(hB + sw256(mt * 16 + l15, s * 32 + quad * 8)));
        acc1[mt] = mfma16(af, bf, acc1[mt]);
      }
    }
    __builtin_amdgcn_s_setprio(0);
  }
  {
    float bias = b1[wave * 16 + l15];            // wave owns hid cols w*16..+15
    #pragma unroll
    for (int mt = 0; mt < 4; mt++)
      #pragma unroll
      for (int r = 0; r < 4; r++) {
        float v = acc1[mt][r] + bias;
        hA[sw64(mt * 16 + quad * 4 + r, wave * 16 + l15)] = f2bfn(v > 0.f ? v : 0.f);
      }
  }
  __syncthreads();                               // h1 visible; hB reads done

  // ===== GEMM2: h2 = relu(h1 @ W2^T + b2); also preload G3 buffers =====
  float rn[16];
  float bias3[4];
  u16x8 mA[8], mB[8];
  {
    u16x8 b2f[4][2];
    float bias2[4];
    #pragma unroll
    for (int nt = 0; nt < 4; nt++) {
      bias2[nt] = b2[wave * 64 + nt * 16 + l15];
      #pragma unroll
      for (int s = 0; s < 2; s++)
        b2f[nt][s] = *((const u16x8*)(w2a + (wave * 8 + nt * 2 + s) * 512 + fragoff));
    }
    #pragma unroll
    for (int h = 0; h < 4; h++) bias3[h] = bmu[wave * 64 + h * 16 + l15];
    LOAD_B3(mA, 0);                              // in flight under G2 compute
    LOAD_B3(mB, 1);
    #pragma unroll
    for (int mt = 0; mt < 4; mt++) {
      u16x8 a0 = *((const u16x8*)(hA + sw64(mt * 16 + l15, 0 + quad * 8)));
      u16x8 a1 = *((const u16x8*)(hA + sw64(mt * 16 + l15, 32 + quad * 8)));
      #pragma unroll
      for (int nt = 0; nt < 4; nt++) {
        f32x4 acc = (f32x4){0.f, 0.f, 0.f, 0.f};
        acc = mfma16(a0, b2f[nt][0], acc);
        acc = mfma16(a1, b2f[nt][1], acc);
        #pragma unroll
        for (int r = 0; r < 4; r++) {
          float v = acc[r] + bias2[nt];
          hB[sw256(mt * 16 + quad * 4 + r, wave * 64 + nt * 16 + l15)] =
              f2bfn(v > 0.f ? v : 0.f);
        }
      }
    }
  }
  __syncthreads();                               // h2s complete; hA is scratch

  float* wnorm = (float*)hA;                     // [4][64] rownorm partials
  float* wkey = (float*)hA + 256;                // [4][64] packed max keys
  int* idxs = (int*)((float*)hA + 512);          // [64]

  // ===== G3 (pipelined halves) + preload of G4's first two groups =====
  #pragma unroll
  for (int i = 0; i < 16; i++) rn[i] = 0.f;
  float mk[16];
  #pragma unroll
  for (int i = 0; i < 16; i++) mk[i] = -3.4e38f;
  u16x8 pA[8], pB[8];
  float cA, cB;
  unsigned iA, iB;

  COMP_B3(mA, 0);
  LOAD_B3(mA, 2);
  COMP_B3(mB, 1);
  LOAD_B3(mB, 3);
  COMP_B3(mA, 2);
  LOAD_P(pA, cA, iA, 0);                         // G4 group 0 under G3 tail
  COMP_B3(mB, 3);
  LOAD_P(pB, cB, iB, 1);                         // G4 group 1

  // rn reduce + wnorm write (VALU/LDS) while pA/pB loads fly
  #pragma unroll
  for (int off = 1; off < 16; off <<= 1)
    #pragma unroll
    for (int i = 0; i < 16; i++) rn[i] += __shfl_xor(rn[i], off, 64);
  if (l15 == 0)
    #pragma unroll
    for (int mt = 0; mt < 4; mt++)
      #pragma unroll
      for (int r = 0; r < 4; r++)
        wnorm[wave * 64 + mt * 16 + quad * 4 + r] = rn[mt * 4 + r];

  // ===== G4: argmax over 16 proto-groups of 16, double-buffered =====
  #pragma unroll
  for (int p = 0; p < 8; p++) {
    COMP_P(pA, cA, iA);
    if (p < 7) LOAD_P(pA, cA, iA, 2 * p + 2);
    COMP_P(pB, cB, iB);
    if (p < 7) LOAD_P(pB, cB, iB, 2 * p + 3);
  }
  #pragma unroll
  for (int off = 1; off < 16; off <<= 1)
    #pragma unroll
    for (int i = 0; i < 16; i++) mk[i] = fmaxf(mk[i], __shfl_xor(mk[i], off, 64));
  if (l15 == 0)
    #pragma unroll
    for (int mt = 0; mt < 4; mt++)
      #pragma unroll
      for (int r = 0; r < 4; r++)
        wkey[wave * 64 + mt * 16 + quad * 4 + r] = mk[mt * 4 + r];
  __syncthreads();

  // ===== final per-row reduce: idx, loss_row = -2*maxkey + ||lat||^2 =====
  if (tid < 64) {
    float k = wkey[tid];
    k = fmaxf(k, wkey[64 + tid]);
    k = fmaxf(k, wkey[128 + tid]);
    k = fmaxf(k, wkey[192 + tid]);
    float nrm = wnorm[tid] + wnorm[64 + tid] + wnorm[128 + tid] + wnorm[192 + tid];
    idxs[tid] = (int)(__builtin_bit_cast(unsigned, k) & 1023u);
    float lrow = nrm - 2.f * k;
    for (int off = 32; off; off >>= 1) lrow += __shfl_xor(lrow, off, 64);
    if (tid == 0) atomicAdd(loss_accum, lrow);
  }
  __syncthreads();

  // ===== epilogue: out = protos[idx]; 8 threads/row -> full 128B lines =====
  {
    #pragma unroll
    for (int half = 0; half < 2; half++) {
      int r = r8 + half * 32;
      int idx = idxs[r];
      const f32x4* qp = (const f32x4*)(protos + (size_t)idx * OUT_D);
      f32x4* op = (f32x4*)(out + (rowbase + r) * OUT_D);
      #pragma unroll
      for (int j = 0; j < 8; j++) {
        f32x4 q = qp[c8 + 8 * j];
        __builtin_nontemporal_store(q, op + c8 + 8 * j);
      }
    }
  }
}

extern "C" void kernel_launch(void* const* d_in, const int* in_sizes, int n_in,
                              void* d_out, int out_size, void* d_ws, size_t ws_size,
                              hipStream_t stream) {
  const float* x = (const float*)d_in[0];
  const float* W1 = (const float*)d_in[1];
  const float* b1 = (const float*)d_in[2];
  const float* W2 = (const float*)d_in[3];
  const float* b2 = (const float*)d_in[4];
  const float* Wmu = (const float*)d_in[5];
  const float* bmu = (const float*)d_in[6];
  const float* protos = (const float*)d_in[7];
  char* ws = (char*)d_ws;
  u16* p2a = (u16*)ws;                           // 512 KB  (frag-order P2)
  u16* w1a = (u16*)(ws + 524288);                // 64 KB   (frag-order W1)
  u16* w2a = (u16*)(ws + 589824);                // 32 KB   (frag-order W2)
  u16* wmua = (u16*)(ws + 622592);               // 128 KB  (frag-order Wmu)
  float* cinit = (float*)(ws + 753664);          // 4 KB
  float* loss = (float*)(ws + 757760);           // 4 B
  float* out = (float*)d_out;

  prep_w<<<dim3(448), dim3(256), 0, stream>>>(W1, W2, Wmu, w1a, w2a, wmua, loss);
  prep_p<<<dim3(256), dim3(256), 0, stream>>>(protos, Wmu, bmu, p2a, cinit);
  vq_fused<<<dim3(2048), dim3(256), 0, stream>>>(x, b1, b2, bmu, protos, w1a, w2a,
                                                 wmua, p2a, cinit, out, loss);
  fin<<<dim3(1), dim3(1), 0, stream>>>(loss, out);
}

// Round 6
// 700.724 us; speedup vs baseline: 1.9019x; 1.9019x over previous
//
#include <hip/hip_runtime.h>

// VQ-VAE fused forward on gfx950 — v6 (un-spill the kernel).
// v4 structure exactly (proto-folded scoring, frag-order weights, 40 KB LDS,
// XCD swizzle, full-line x/out requests). Two changes:
//  - amdgpu_waves_per_eu(4,4): pin allocator occupancy target to 4 waves/EU.
//    v2-v5 compiled to 64 VGPRs (allocator chased 8 waves/EU, unreachable due
//    to the 40KB-LDS cap) and spilled ~150KB/block to scratch — the symmetric
//    +FETCH/+WRITE inflation seen in every round since v2.
//  - W1 frags streamed as alternating named pairs (distance-2 prefetch)
//    instead of 16 resident frags, capping peak live set ≈110 < 128.

typedef unsigned short u16;
typedef float f32x4 __attribute__((ext_vector_type(4)));
typedef __bf16 bf16x8 __attribute__((ext_vector_type(8)));
typedef unsigned short u16x8 __attribute__((ext_vector_type(8)));
typedef unsigned short u16x4 __attribute__((ext_vector_type(4)));

#define N_ROWS 131072
#define IN_D 512
#define HID_D 64
#define OUT_D 256
#define K_P 1024

__device__ __forceinline__ u16 f2bfn(float f) {
  return __builtin_bit_cast(u16, (__bf16)f);
}
__device__ __forceinline__ f32x4 mfma16(u16x8 a, u16x8 b, f32x4 c) {
  return __builtin_amdgcn_mfma_f32_16x16x32_bf16(
      __builtin_bit_cast(bf16x8, a), __builtin_bit_cast(bf16x8, b), c, 0, 0, 0);
}
// XOR-swizzled LDS addressing (u16 units), 8-col chunks stay contiguous.
__device__ __forceinline__ int sw64(int row, int col) {   // [64][64]
  return row * 64 + ((((col >> 3) ^ (row & 7)) & 7) << 3) + (col & 7);
}
__device__ __forceinline__ int sw256(int row, int col) {  // [64][256]
  return row * 256 + ((((col >> 3) ^ (row & 15)) & 31) << 3) + (col & 7);
}

// ---------------- prep kernels (unchanged from v4) ----------------
__global__ void prep_w(const float* __restrict__ W1, const float* __restrict__ W2,
                       const float* __restrict__ Wmu, u16* __restrict__ w1a,
                       u16* __restrict__ w2a, u16* __restrict__ wmua,
                       float* __restrict__ loss_accum) {
  int i = blockIdx.x * 256 + threadIdx.x;   // grid 448*256 = 114688 exactly
  if (i == 0) *loss_accum = 0.f;
  if (i < 32768) {                          // W1: f = w*16+s  (64 frags)
    int a = i;
    int f = a >> 9, r = (a >> 5) & 15, c = a & 31;
    int w = f >> 4, s = f & 15;
    w1a[a] = f2bfn(W1[(w * 16 + r) * IN_D + s * 32 + c]);
  } else if (i < 49152) {                   // W2: f = w*8+nt*2+s  (32 frags)
    int a = i - 32768;
    int f = a >> 9, r = (a >> 5) & 15, c = a & 31;
    int w = f >> 3, nt = (f >> 1) & 3, s = f & 1;
    w2a[a] = f2bfn(W2[(w * 64 + nt * 16 + r) * HID_D + s * 32 + c]);
  } else {                                  // Wmu: f = w*32+g2*8+s (128 frags)
    int a = i - 49152;
    int f = a >> 9, r = (a >> 5) & 15, c = a & 31;
    int w = f >> 5, g2 = (f >> 3) & 3, s = f & 7;
    wmua[a] = f2bfn(Wmu[(w * 64 + g2 * 16 + r) * OUT_D + s * 32 + c]);
  }
}

__global__ void prep_p(const float* __restrict__ protos, const float* __restrict__ Wmu,
                       const float* __restrict__ bmu, u16* __restrict__ p2a,
                       float* __restrict__ cinit) {
  __shared__ float prow[4][256];
  const int b = blockIdx.x, t = threadIdx.x;   // 256 blocks x 4 protos
  const int wv = t >> 6, lane = t & 63;
  #pragma unroll
  for (int i = 0; i < 4; i++) prow[i][t] = protos[(b * 4 + i) * 256 + t];
  __syncthreads();
  float acc[4] = {0.f, 0.f, 0.f, 0.f};
  #pragma unroll 4
  for (int j = 0; j < 256; j++) {
    float w = Wmu[j * 256 + t];
    acc[0] += prow[0][j] * w; acc[1] += prow[1][j] * w;
    acc[2] += prow[2][j] * w; acc[3] += prow[3][j] * w;
  }
  #pragma unroll
  for (int i = 0; i < 4; i++) {
    int p = b * 4 + i;
    int f = (p >> 8) * 128 + ((p >> 5) & 7) * 16 + ((p >> 4) & 1) * 8 + (t >> 5);
    p2a[f * 512 + (p & 15) * 32 + (t & 31)] = f2bfn(acc[i]);
  }
  float part = 0.f;
  #pragma unroll
  for (int c = 0; c < 4; c++) {
    float v = prow[wv][lane + c * 64];
    part += v * bmu[lane + c * 64] - 0.5f * v * v;
  }
  for (int off = 32; off; off >>= 1) part += __shfl_xor(part, off, 64);
  if (lane == 0) cinit[b * 4 + wv] = part;
}

__global__ void fin(const float* __restrict__ loss_accum, float* __restrict__ out) {
  out[(size_t)N_ROWS * OUT_D] = loss_accum[0] * (1.25f / ((float)N_ROWS * (float)OUT_D));
  out[(size_t)N_ROWS * OUT_D + 1] = 0.f;  // capacity
}

// ---------------- fused main kernel ----------------
__global__ __attribute__((amdgpu_waves_per_eu(4, 4))) __launch_bounds__(256)
void vq_fused(
    const float* __restrict__ x, const float* __restrict__ b1,
    const float* __restrict__ b2, const float* __restrict__ bmu,
    const float* __restrict__ protos, const u16* __restrict__ w1a,
    const u16* __restrict__ w2a, const u16* __restrict__ wmua,
    const u16* __restrict__ p2a, const float* __restrict__ cinit,
    float* __restrict__ out, float* __restrict__ loss_accum) {
  __shared__ uint4 smem4[2560];                  // 40 KB exactly -> 4 blocks/CU
  u16* hA = (u16*)smem4;                         // 8 KB: xs chunk -> h1 -> scratch
  u16* hB = (u16*)smem4 + 4096;                  // 32 KB: h2s [64][256]

  const int tid = threadIdx.x;
  const int wave = tid >> 6;
  const int lane = tid & 63;
  const int quad = lane >> 4;
  const int l15 = lane & 15;
  const int fragoff = l15 * 32 + quad * 8;       // lane offset in a 512-u16 frag
  const int bid = blockIdx.x;
  const int swz = (bid & 7) * 256 + (bid >> 3);  // bijective XCD swizzle
  const long rowbase = (long)swz * 64;

  // ===== GEMM1: h1 = relu(x @ W1^T + b1); K=512 in 8 chunks of 64 =====
  // W1 frags streamed as alternating named pairs, distance-2 prefetch.
  const u16* w1base = w1a + wave * 16 * 512 + fragoff;
  u16x8 wA0 = *((const u16x8*)(w1base + 0 * 512));
  u16x8 wA1 = *((const u16x8*)(w1base + 1 * 512));
  u16x8 wB0 = *((const u16x8*)(w1base + 2 * 512));
  u16x8 wB1 = *((const u16x8*)(w1base + 3 * 512));

  f32x4 acc1[4];
  #pragma unroll
  for (int mt = 0; mt < 4; mt++) acc1[mt] = (f32x4){0.f, 0.f, 0.f, 0.f};

  // stage map: 8 threads/row, two row-halves; per instr 8 rows x 128B full lines
  const int r8 = tid >> 3, c8 = tid & 7;
  const float* xr0 = x + (rowbase + r8) * IN_D;
  const float* xr1 = x + (rowbase + r8 + 32) * IN_D;
  f32x4 xv[4];
  xv[0] = __builtin_nontemporal_load((const f32x4*)xr0 + c8);
  xv[1] = __builtin_nontemporal_load((const f32x4*)xr0 + c8 + 8);
  xv[2] = __builtin_nontemporal_load((const f32x4*)xr1 + c8);
  xv[3] = __builtin_nontemporal_load((const f32x4*)xr1 + c8 + 8);

  #pragma unroll
  for (int kc = 0; kc < 8; kc++) {
    u16x4 hv[4];
    #pragma unroll
    for (int q = 0; q < 4; q++) {
      hv[q][0] = f2bfn(xv[q][0]); hv[q][1] = f2bfn(xv[q][1]);
      hv[q][2] = f2bfn(xv[q][2]); hv[q][3] = f2bfn(xv[q][3]);
    }
    if (kc < 7) {                                // prefetch next x chunk (T14)
      const int base = (kc + 1) * 16;
      xv[0] = __builtin_nontemporal_load((const f32x4*)xr0 + base + c8);
      xv[1] = __builtin_nontemporal_load((const f32x4*)xr0 + base + c8 + 8);
      xv[2] = __builtin_nontemporal_load((const f32x4*)xr1 + base + c8);
      xv[3] = __builtin_nontemporal_load((const f32x4*)xr1 + base + c8 + 8);
    }
    __syncthreads();                             // prev chunk's frag reads done
    *((u16x4*)(hA + sw64(r8, c8 * 4))) = hv[0];
    *((u16x4*)(hA + sw64(r8, c8 * 4 + 32))) = hv[1];
    *((u16x4*)(hA + sw64(r8 + 32, c8 * 4))) = hv[2];
    *((u16x4*)(hA + sw64(r8 + 32, c8 * 4 + 32))) = hv[3];
    __syncthreads();
    {
      u16x8 bf0 = (kc & 1) ? wB0 : wA0;          // kc is unroll-constant
      u16x8 bf1 = (kc & 1) ? wB1 : wA1;
      #pragma unroll
      for (int mt = 0; mt < 4; mt++) {
        u16x8 af = *((const u16x8*)(hA + sw64(mt * 16 + l15, 0 + quad * 8)));
        acc1[mt] = mfma16(af, bf0, acc1[mt]);
      }
      #pragma unroll
      for (int mt = 0; mt < 4; mt++) {
        u16x8 af = *((const u16x8*)(hA + sw64(mt * 16 + l15, 32 + quad * 8)));
        acc1[mt] = mfma16(af, bf1, acc1[mt]);
      }
    }
    if (kc < 6) {                                // reload consumed pair for kc+2
      if (kc & 1) {
        wB0 = *((const u16x8*)(w1base + ((kc + 2) * 2 + 0) * 512));
        wB1 = *((const u16x8*)(w1base + ((kc + 2) * 2 + 1) * 512));
      } else {
        wA0 = *((const u16x8*)(w1base + ((kc + 2) * 2 + 0) * 512));
        wA1 = *((const u16x8*)(w1base + ((kc + 2) * 2 + 1) * 512));
      }
    }
  }
  __syncthreads();                               // xs dead; hA becomes h1
  {
    float bias = b1[wave * 16 + l15];            // wave owns hid cols w*16..+15
    #pragma unroll
    for (int mt = 0; mt < 4; mt++)
      #pragma unroll
      for (int r = 0; r < 4; r++) {
        float v = acc1[mt][r] + bias;
        hA[sw64(mt * 16 + quad * 4 + r, wave * 16 + l15)] = f2bfn(v > 0.f ? v : 0.f);
      }
  }
  __syncthreads();                               // h1 complete

  // ===== GEMM2: h2 = relu(h1 @ W2^T + b2), K=64; wave owns cols w*64..+63 =====
  {
    u16x8 b2f[4][2];
    float bias2[4];
    #pragma unroll
    for (int nt = 0; nt < 4; nt++) {
      bias2[nt] = b2[wave * 64 + nt * 16 + l15];
      #pragma unroll
      for (int s = 0; s < 2; s++)
        b2f[nt][s] = *((const u16x8*)(w2a + (wave * 8 + nt * 2 + s) * 512 + fragoff));
    }
    #pragma unroll
    for (int mt = 0; mt < 4; mt++) {
      u16x8 a0 = *((const u16x8*)(hA + sw64(mt * 16 + l15, 0 + quad * 8)));
      u16x8 a1 = *((const u16x8*)(hA + sw64(mt * 16 + l15, 32 + quad * 8)));
      #pragma unroll
      for (int nt = 0; nt < 4; nt++) {
        f32x4 acc = (f32x4){0.f, 0.f, 0.f, 0.f};
        acc = mfma16(a0, b2f[nt][0], acc);
        acc = mfma16(a1, b2f[nt][1], acc);
        #pragma unroll
        for (int r = 0; r < 4; r++) {
          float v = acc[r] + bias2[nt];
          hB[sw256(mt * 16 + quad * 4 + r, wave * 64 + nt * 16 + l15)] =
              f2bfn(v > 0.f ? v : 0.f);
        }
      }
    }
  }
  __syncthreads();                               // h2s complete; hA free (scratch)

  float* wnorm = (float*)hA;                     // [4][64] rownorm partials
  float* wkey = (float*)hA + 256;                // [4][64] packed max keys
  int* idxs = (int*)((float*)hA + 512);          // [64]

  // ===== G3: lat in regs -> rownorm partials (wave owns cols w*64..+63) =====
  {
    float rn[16];
    #pragma unroll
    for (int i = 0; i < 16; i++) rn[i] = 0.f;
    #pragma unroll
    for (int np = 0; np < 2; np++) {
      u16x8 b3f[2][8];
      float bias3[2];
      #pragma unroll
      for (int tt = 0; tt < 2; tt++) {
        bias3[tt] = bmu[wave * 64 + (np * 2 + tt) * 16 + l15];
        #pragma unroll
        for (int s = 0; s < 8; s++)
          b3f[tt][s] = *((const u16x8*)(wmua +
              ((wave * 4 + np * 2 + tt) * 8 + s) * 512 + fragoff));
      }
      #pragma unroll
      for (int mt = 0; mt < 4; mt++) {
        f32x4 aa = (f32x4){0.f, 0.f, 0.f, 0.f}, ab = (f32x4){0.f, 0.f, 0.f, 0.f};
        #pragma unroll
        for (int s = 0; s < 8; s++) {
          u16x8 af = *((const u16x8*)(hB + sw256(mt * 16 + l15, s * 32 + quad * 8)));
          aa = mfma16(af, b3f[0][s], aa);
          ab = mfma16(af, b3f[1][s], ab);
        }
        #pragma unroll
        for (int r = 0; r < 4; r++) {
          float v0 = aa[r] + bias3[0];           // NO relu on lat
          float v1 = ab[r] + bias3[1];
          rn[mt * 4 + r] += v0 * v0 + v1 * v1;
        }
      }
    }
    #pragma unroll
    for (int off = 1; off < 16; off <<= 1)
      #pragma unroll
      for (int i = 0; i < 16; i++) rn[i] += __shfl_xor(rn[i], off, 64);
    if (l15 == 0)
      #pragma unroll
      for (int mt = 0; mt < 4; mt++)
        #pragma unroll
        for (int r = 0; r < 4; r++)
          wnorm[wave * 64 + mt * 16 + quad * 4 + r] = rn[mt * 4 + r];
  }

  // ===== G4: argmax_p (h2.P2[p] + cinit[p]); wave owns protos w*256..+255 =====
  {
    float mk[16];
    #pragma unroll
    for (int i = 0; i < 16; i++) mk[i] = -3.4e38f;
    #pragma unroll
    for (int g = 0; g < 8; g++) {
      int p0 = wave * 256 + g * 32;
      u16x8 bpf[2][8];
      #pragma unroll
      for (int tt = 0; tt < 2; tt++)
        #pragma unroll
        for (int s = 0; s < 8; s++)
          bpf[tt][s] = *((const u16x8*)(p2a +
              (wave * 128 + g * 16 + tt * 8 + s) * 512 + fragoff));
      float c0 = cinit[p0 + l15];
      float c1 = cinit[p0 + 16 + l15];
      unsigned i0 = (unsigned)(p0 + l15), i1 = (unsigned)(p0 + 16 + l15);
      #pragma unroll
      for (int mt = 0; mt < 4; mt++) {
        f32x4 aa = (f32x4){c0, c0, c0, c0};
        f32x4 ab = (f32x4){c1, c1, c1, c1};
        #pragma unroll
        for (int s = 0; s < 8; s++) {
          u16x8 af = *((const u16x8*)(hB + sw256(mt * 16 + l15, s * 32 + quad * 8)));
          aa = mfma16(af, bpf[0][s], aa);
          ab = mfma16(af, bpf[1][s], ab);
        }
        #pragma unroll
        for (int r = 0; r < 4; r++) {
          unsigned ka = (__builtin_bit_cast(unsigned, aa[r]) & 0xFFFFFC00u) | i0;
          unsigned kb = (__builtin_bit_cast(unsigned, ab[r]) & 0xFFFFFC00u) | i1;
          mk[mt * 4 + r] = fmaxf(fmaxf(mk[mt * 4 + r], __builtin_bit_cast(float, ka)),
                                 __builtin_bit_cast(float, kb));
        }
      }
    }
    #pragma unroll
    for (int off = 1; off < 16; off <<= 1)
      #pragma unroll
      for (int i = 0; i < 16; i++) mk[i] = fmaxf(mk[i], __shfl_xor(mk[i], off, 64));
    if (l15 == 0)
      #pragma unroll
      for (int mt = 0; mt < 4; mt++)
        #pragma unroll
        for (int r = 0; r < 4; r++)
          wkey[wave * 64 + mt * 16 + quad * 4 + r] = mk[mt * 4 + r];
  }
  __syncthreads();

  // ===== final per-row reduce: idx, loss_row = -2*maxkey + ||lat||^2 =====
  if (tid < 64) {
    float k = wkey[tid];
    k = fmaxf(k, wkey[64 + tid]);
    k = fmaxf(k, wkey[128 + tid]);
    k = fmaxf(k, wkey[192 + tid]);
    float nrm = wnorm[tid] + wnorm[64 + tid] + wnorm[128 + tid] + wnorm[192 + tid];
    idxs[tid] = (int)(__builtin_bit_cast(unsigned, k) & 1023u);
    float lrow = nrm - 2.f * k;
    for (int off = 32; off; off >>= 1) lrow += __shfl_xor(lrow, off, 64);
    if (tid == 0) atomicAdd(loss_accum, lrow);
  }
  __syncthreads();

  // ===== epilogue: out = protos[idx]; 8 threads/row -> full 128B lines =====
  {
    #pragma unroll
    for (int half = 0; half < 2; half++) {
      int r = r8 + half * 32;
      int idx = idxs[r];
      const f32x4* qp = (const f32x4*)(protos + (size_t)idx * OUT_D);
      f32x4* op = (f32x4*)(out + (rowbase + r) * OUT_D);
      #pragma unroll
      for (int j = 0; j < 8; j++) {
        f32x4 q = qp[c8 + 8 * j];
        __builtin_nontemporal_store(q, op + c8 + 8 * j);
      }
    }
  }
}

extern "C" void kernel_launch(void* const* d_in, const int* in_sizes, int n_in,
                              void* d_out, int out_size, void* d_ws, size_t ws_size,
                              hipStream_t stream) {
  const float* x = (const float*)d_in[0];
  const float* W1 = (const float*)d_in[1];
  const float* b1 = (const float*)d_in[2];
  const float* W2 = (const float*)d_in[3];
  const float* b2 = (const float*)d_in[4];
  const float* Wmu = (const float*)d_in[5];
  const float* bmu = (const float*)d_in[6];
  const float* protos = (const float*)d_in[7];
  char* ws = (char*)d_ws;
  u16* p2a = (u16*)ws;                           // 512 KB  (frag-order P2)
  u16* w1a = (u16*)(ws + 524288);                // 64 KB   (frag-order W1)
  u16* w2a = (u16*)(ws + 589824);                // 32 KB   (frag-order W2)
  u16* wmua = (u16*)(ws + 622592);               // 128 KB  (frag-order Wmu)
  float* cinit = (float*)(ws + 753664);          // 4 KB
  float* loss = (float*)(ws + 757760);           // 4 B
  float* out = (float*)d_out;

  prep_w<<<dim3(448), dim3(256), 0, stream>>>(W1, W2, Wmu, w1a, w2a, wmua, loss);
  prep_p<<<dim3(256), dim3(256), 0, stream>>>(protos, Wmu, bmu, p2a, cinit);
  vq_fused<<<dim3(2048), dim3(256), 0, stream>>>(x, b1, b2, bmu, protos, w1a, w2a,
                                                 wmua, p2a, cinit, out, loss);
  fin<<<dim3(1), dim3(1), 0, stream>>>(loss, out);
}